// Round 9
// baseline (245.575 us; speedup 1.0000x reference)
//
#include <hip/hip_runtime.h>
#include <math.h>

#define B_N 8192
#define K_N 256
#define D_N 768
#define BM 32
#define KC 32
#define RPB 4   // rows per k_row block

static constexpr float ALPHA_C = 0.2f;
static constexpr float BETA_C  = 0.3f;
static constexpr float EPS_C   = 1e-8f;
static constexpr float NEG_INF_C = -10000.0f;
static constexpr float INV_WTEMP = 20.0f;   // 1/0.05

// ---------------------------------------------------------------------------
// K0: normalize centroid rows, write TRANSPOSED CnT[768][256] into ws
// ---------------------------------------------------------------------------
__global__ __launch_bounds__(256) void k_centroid_prep(
        const float* __restrict__ centroid, float* __restrict__ cnt) {
    int c = blockIdx.x, t = threadIdx.x;
    const float* p = centroid + c * D_N;
    float v0 = p[t], v1 = p[t + 256], v2 = p[t + 512];
    float s = v0 * v0 + v1 * v1 + v2 * v2;
    #pragma unroll
    for (int o = 32; o >= 1; o >>= 1) s += __shfl_xor(s, o);
    __shared__ float red[4];
    __shared__ float sinv;
    if ((t & 63) == 0) red[t >> 6] = s;
    __syncthreads();
    if (t == 0)
        sinv = 1.0f / fmaxf(sqrtf(red[0] + red[1] + red[2] + red[3]), EPS_C);
    __syncthreads();
    float inv = sinv;
    cnt[(t)       * K_N + c] = v0 * inv;
    cnt[(t + 256) * K_N + c] = v1 * inv;
    cnt[(t + 512) * K_N + c] = v2 * inv;
}

// ---------------------------------------------------------------------------
// K1: fused intra GEMM + row-norm + top-2 + centroid gather — EXACT round-4
// version (measured-good). Untouched.
// ---------------------------------------------------------------------------
__device__ __forceinline__ bool top_better(float v, int iv, float w, int iw) {
    return (v > w) || ((v == w) && (iv < iw));
}

__global__ __launch_bounds__(256) void k_intra(
        const float* __restrict__ dp, const float* __restrict__ cnt,
        const float* __restrict__ centroid,
        float* __restrict__ out_intra, unsigned char* __restrict__ cid_g,
        float* __restrict__ dp_centroid, float* __restrict__ hard_negative) {
    __shared__ float ct[KC][K_N];        // 32 KB
    __shared__ float dpt[KC][BM + 4];    // 4.6 KB, row stride 144 B (16B-aligned)
    __shared__ float sqp[BM][8];
    __shared__ float rn[BM];
    int t = threadIdx.x;
    int row0 = blockIdx.x * BM;
    int tx = t & 63, ty = t >> 6;
    int c0 = tx * 4;
    int r0 = ty * 8;
    int sr = t >> 3, skq = t & 7;

    float acc[8][4];
    #pragma unroll
    for (int r = 0; r < 8; ++r)
        #pragma unroll
        for (int c = 0; c < 4; ++c) acc[r][c] = 0.f;
    float ss = 0.f;

    for (int kb = 0; kb < D_N; kb += KC) {
        __syncthreads();
        #pragma unroll
        for (int u = 0; u < 8; ++u) {
            int f4 = t + 256 * u;                 // 0..2047
            int k = f4 >> 6, c4 = (f4 & 63) << 2;
            *(float4*)&ct[k][c4] = *(const float4*)&cnt[(size_t)(kb + k) * K_N + c4];
        }
        {
            float4 v = *(const float4*)&dp[(size_t)(row0 + sr) * D_N + kb + skq * 4];
            ss += v.x * v.x + v.y * v.y + v.z * v.z + v.w * v.w;
            dpt[skq * 4 + 0][sr] = v.x;
            dpt[skq * 4 + 1][sr] = v.y;
            dpt[skq * 4 + 2][sr] = v.z;
            dpt[skq * 4 + 3][sr] = v.w;
        }
        __syncthreads();
        #pragma unroll
        for (int k = 0; k < KC; ++k) {
            float4 b4 = *(float4*)&ct[k][c0];
            float4 a0 = *(float4*)&dpt[k][r0];
            float4 a1 = *(float4*)&dpt[k][r0 + 4];
            float a[8] = {a0.x, a0.y, a0.z, a0.w, a1.x, a1.y, a1.z, a1.w};
            float b[4] = {b4.x, b4.y, b4.z, b4.w};
            #pragma unroll
            for (int r = 0; r < 8; ++r)
                #pragma unroll
                for (int c = 0; c < 4; ++c)
                    acc[r][c] += a[r] * b[c];
        }
    }

    // row norms
    sqp[sr][skq] = ss;
    __syncthreads();
    if (t < BM) {
        float s = 0.f;
        #pragma unroll
        for (int j = 0; j < 8; ++j) s += sqp[t][j];
        rn[t] = 1.0f / fmaxf(sqrtf(s), EPS_C);
    }
    __syncthreads();

    // per row: scale+store intra, wave top-2, cid + gather
    #pragma unroll 1
    for (int r = 0; r < 8; ++r) {
        int row = row0 + r0 + r;
        float rv = rn[r0 + r];
        float4 o;
        o.x = acc[r][0] * rv; o.y = acc[r][1] * rv;
        o.z = acc[r][2] * rv; o.w = acc[r][3] * rv;
        *(float4*)&out_intra[(size_t)row * K_N + c0] = o;

        float m1 = o.x, m2 = -1e30f;
        int i1 = c0, i2 = K_N;
        { float v = o.y; int id = c0 + 1;
          if (v > m1) { m2 = m1; i2 = i1; m1 = v; i1 = id; } else if (v > m2) { m2 = v; i2 = id; } }
        { float v = o.z; int id = c0 + 2;
          if (v > m1) { m2 = m1; i2 = i1; m1 = v; i1 = id; } else if (v > m2) { m2 = v; i2 = id; } }
        { float v = o.w; int id = c0 + 3;
          if (v > m1) { m2 = m1; i2 = i1; m1 = v; i1 = id; } else if (v > m2) { m2 = v; i2 = id; } }
        #pragma unroll
        for (int off = 32; off >= 1; off >>= 1) {
            float om1 = __shfl_xor(m1, off);
            int   oi1 = __shfl_xor(i1, off);
            float om2 = __shfl_xor(m2, off);
            int   oi2 = __shfl_xor(i2, off);
            if (top_better(om1, oi1, m1, i1)) {
                if (top_better(m1, i1, om2, oi2)) { m2 = m1; i2 = i1; }
                else                              { m2 = om2; i2 = oi2; }
                m1 = om1; i1 = oi1;
            } else if (top_better(om1, oi1, m2, i2)) {
                m2 = om1; i2 = oi1;
            }
        }
        if (tx == 0) cid_g[row] = (unsigned char)i1;

        const float4* s1 = (const float4*)(centroid + (size_t)i1 * D_N);
        const float4* s2 = (const float4*)(centroid + (size_t)i2 * D_N);
        float4* d1 = (float4*)(dp_centroid   + (size_t)row * D_N);
        float4* d2 = (float4*)(hard_negative + (size_t)row * D_N);
        #pragma unroll
        for (int u = 0; u < 3; ++u) {
            d1[tx + 64 * u] = s1[tx + 64 * u];
            d2[tx + 64 * u] = s2[tx + 64 * u];
        }
    }
}

// ---------------------------------------------------------------------------
// K3 v4: 4 rows per block, depth-1 software pipeline.
// Next row's loads issue BEFORE current row's se-barrier + weights stores;
// cid words loaded once per block; pos + row-cids hoisted to uniform preloads
// (no posb barrier). 1 barrier per row (disjoint red_se slots). grid = 2048.
// ---------------------------------------------------------------------------
__global__ __launch_bounds__(256) void k_row(
        const float* __restrict__ bcs, const unsigned char* __restrict__ cid_g,
        float* __restrict__ dp_cluster, float* __restrict__ weights,
        float* __restrict__ partials) {
    int i0 = blockIdx.x * RPB;
    int t = threadIdx.x;
    __shared__ float red_se[RPB][4];
    __shared__ float red_fn[4];
    const unsigned* cidw = (const unsigned*)cid_g;

    // uniform preloads: 4 row-cids (one word, i0 is 4-aligned) + 4 diag elems
    unsigned mycw = cidw[i0 >> 2];
    float pos0 = bcs[(size_t)(i0 + 0) * B_N + (i0 + 0)];
    float pos1 = bcs[(size_t)(i0 + 1) * B_N + (i0 + 1)];
    float pos2 = bcs[(size_t)(i0 + 2) * B_N + (i0 + 2)];
    float pos3 = bcs[(size_t)(i0 + 3) * B_N + (i0 + 3)];

    // cid words: loaded once, reused for all 4 rows
    unsigned cw[8];
    #pragma unroll
    for (int u = 0; u < 8; ++u) cw[u] = cidw[t + 256 * u];

    float4 va[8], vb[8];
    {
        const float4* s0 = (const float4*)(bcs + (size_t)i0 * B_N);
        #pragma unroll
        for (int u = 0; u < 8; ++u) va[u] = s0[t + 256 * u];
    }

    float fnacc = 0.f;

#define ROW_PHASE(R, CUR, NXT, POS)                                            \
    {                                                                          \
        int i = i0 + R;                                                        \
        if (R < RPB - 1) {                                                     \
            const float4* sn = (const float4*)(bcs + (size_t)(i + 1) * B_N);   \
            _Pragma("unroll")                                                  \
            for (int u = 0; u < 8; ++u) NXT[u] = sn[t + 256 * u];              \
        }                                                                      \
        unsigned myc = (mycw >> (R * 8)) & 255u;                               \
        float pos = POS;                                                       \
        float fn = 0.f, se = 0.f;                                              \
        float* dcrow = dp_cluster + (size_t)i * B_N;                           \
        _Pragma("unroll")                                                      \
        for (int u = 0; u < 8; ++u) {                                          \
            int f4 = t + 256 * u; int j0 = f4 * 4; unsigned c = cw[u];         \
            float4 w = CUR[u], e, dc;                                          \
            bool b0 = ((c        & 255u) == myc) & (j0     != i);              \
            bool b1 = (((c >> 8) & 255u) == myc) & (j0 + 1 != i);              \
            bool b2 = (((c >> 16)& 255u) == myc) & (j0 + 2 != i);              \
            bool b3 = (((c >> 24)& 255u) == myc) & (j0 + 3 != i);              \
            float d0 = b0 ? (w.x - pos) : 0.f, d1 = b1 ? (w.y - pos) : 0.f;    \
            float d2 = b2 ? (w.z - pos) : 0.f, d3 = b3 ? (w.w - pos) : 0.f;    \
            fn += fmaxf(d0 + ALPHA_C, 0.f) + fmaxf(-d0 - BETA_C, 0.f);         \
            fn += fmaxf(d1 + ALPHA_C, 0.f) + fmaxf(-d1 - BETA_C, 0.f);         \
            fn += fmaxf(d2 + ALPHA_C, 0.f) + fmaxf(-d2 - BETA_C, 0.f);         \
            fn += fmaxf(d3 + ALPHA_C, 0.f) + fmaxf(-d3 - BETA_C, 0.f);         \
            dc.x = b0 ? 1.f : 0.f; dc.y = b1 ? 1.f : 0.f;                      \
            dc.z = b2 ? 1.f : 0.f; dc.w = b3 ? 1.f : 0.f;                      \
            e.x = __expf((j0     == i) ? NEG_INF_C : w.x);                     \
            e.y = __expf((j0 + 1 == i) ? NEG_INF_C : w.y);                     \
            e.z = __expf((j0 + 2 == i) ? NEG_INF_C : w.z);                     \
            e.w = __expf((j0 + 3 == i) ? NEG_INF_C : w.w);                     \
            se += e.x + e.y + e.z + e.w;                                       \
            CUR[u] = e;                                                        \
            ((float4*)dcrow)[f4] = dc;                                         \
        }                                                                      \
        fnacc += fn;                                                           \
        _Pragma("unroll")                                                      \
        for (int o = 32; o >= 1; o >>= 1) se += __shfl_xor(se, o);             \
        if ((t & 63) == 0) red_se[R][t >> 6] = se;                             \
        __syncthreads();                                                       \
        se = red_se[R][0] + red_se[R][1] + red_se[R][2] + red_se[R][3];        \
        float inv = INV_WTEMP / se;                                            \
        float* wrow = weights + (size_t)i * B_N;                               \
        _Pragma("unroll")                                                      \
        for (int u = 0; u < 8; ++u) {                                          \
            int j0 = (t + 256 * u) * 4;                                        \
            wrow[j0]     = CUR[u].x * inv; wrow[j0 + 1] = CUR[u].y * inv;      \
            wrow[j0 + 2] = CUR[u].z * inv; wrow[j0 + 3] = CUR[u].w * inv;      \
        }                                                                      \
    }

    ROW_PHASE(0, va, vb, pos0)
    ROW_PHASE(1, vb, va, pos1)
    ROW_PHASE(2, va, vb, pos2)
    ROW_PHASE(3, vb, va, pos3)
#undef ROW_PHASE

    // block fn partial (one extra barrier at end)
    #pragma unroll
    for (int o = 32; o >= 1; o >>= 1) fnacc += __shfl_xor(fnacc, o);
    if ((t & 63) == 0) red_fn[t >> 6] = fnacc;
    __syncthreads();
    if (t == 0)
        partials[blockIdx.x] = red_fn[0] + red_fn[1] + red_fn[2] + red_fn[3];
}

// ---------------------------------------------------------------------------
// K4: reduce 2048 per-block partials -> fn_loss (fixed order, deterministic)
// ---------------------------------------------------------------------------
__global__ __launch_bounds__(256) void k_final(
        const float* __restrict__ partials, float* __restrict__ out) {
    int t = threadIdx.x;
    __shared__ double red[4];
    double s = 0.0;
    #pragma unroll
    for (int u = 0; u < 8; ++u) s += (double)partials[t + 256 * u];
    #pragma unroll
    for (int o = 32; o >= 1; o >>= 1) s += __shfl_xor(s, o);
    if ((t & 63) == 0) red[t >> 6] = s;
    __syncthreads();
    if (t == 0)
        out[0] = (float)((red[0] + red[1] + red[2] + red[3])
                         / ((double)B_N * (double)B_N));
}

// ---------------------------------------------------------------------------
extern "C" void kernel_launch(void* const* d_in, const int* in_sizes, int n_in,
                              void* d_out, int out_size, void* d_ws, size_t ws_size,
                              hipStream_t stream) {
    const float* dp       = (const float*)d_in[0];
    const float* centroid = (const float*)d_in[1];
    const float* bcs      = (const float*)d_in[2];
    float* out = (float*)d_out;

    float* intra       = out;                       // [8192,256]
    float* dp_cluster  = out + 2097152;             // [8192,8192]
    float* dp_centroid = out + 69206016;            // [8192,768]
    float* hard_neg    = out + 75497472;            // [8192,768]
    float* fn_out      = out + 81788928;            // [1]
    float* weights     = out + 81788929;            // [8192,8192]

    char* ws = (char*)d_ws;
    float*         cnt      = (float*)(ws + 256);                      // 768*256*4
    unsigned char* cid      = (unsigned char*)(ws + 256 + 786432);     // 8192
    float*         partials = (float*)(ws + 256 + 786432 + 8192);      // 8192

    k_centroid_prep<<<K_N, 256, 0, stream>>>(centroid, cnt);
    k_intra<<<B_N / BM, 256, 0, stream>>>(dp, cnt, centroid, intra, cid,
                                          dp_centroid, hard_neg);
    k_row<<<B_N / RPB, 256, 0, stream>>>(bcs, cid, dp_cluster, weights, partials);
    k_final<<<1, 256, 0, stream>>>(partials, fn_out);
}

// Round 10
// 226.488 us; speedup vs baseline: 1.0843x; 1.0843x over previous
//
#include <hip/hip_runtime.h>
#include <math.h>

#define B_N 8192
#define K_N 256
#define D_N 768
#define BM 32
#define KC 32

static constexpr float ALPHA_C = 0.2f;
static constexpr float BETA_C  = 0.3f;
static constexpr float EPS_C   = 1e-8f;
static constexpr float NEG_INF_C = -10000.0f;
static constexpr float INV_WTEMP = 20.0f;   // 1/0.05

typedef __attribute__((ext_vector_type(4))) float f4v;

// ---------------------------------------------------------------------------
// K0: normalize centroid rows, write TRANSPOSED CnT[768][256] into ws
// ---------------------------------------------------------------------------
__global__ __launch_bounds__(256) void k_centroid_prep(
        const float* __restrict__ centroid, float* __restrict__ cnt) {
    int c = blockIdx.x, t = threadIdx.x;
    const float* p = centroid + c * D_N;
    float v0 = p[t], v1 = p[t + 256], v2 = p[t + 512];
    float s = v0 * v0 + v1 * v1 + v2 * v2;
    #pragma unroll
    for (int o = 32; o >= 1; o >>= 1) s += __shfl_xor(s, o);
    __shared__ float red[4];
    __shared__ float sinv;
    if ((t & 63) == 0) red[t >> 6] = s;
    __syncthreads();
    if (t == 0)
        sinv = 1.0f / fmaxf(sqrtf(red[0] + red[1] + red[2] + red[3]), EPS_C);
    __syncthreads();
    float inv = sinv;
    cnt[(t)       * K_N + c] = v0 * inv;
    cnt[(t + 256) * K_N + c] = v1 * inv;
    cnt[(t + 512) * K_N + c] = v2 * inv;
}

// ---------------------------------------------------------------------------
// K1: fused intra GEMM + row-norm + top-2 + centroid gather — EXACT round-4
// version (measured-good). Untouched.
// ---------------------------------------------------------------------------
__device__ __forceinline__ bool top_better(float v, int iv, float w, int iw) {
    return (v > w) || ((v == w) && (iv < iw));
}

__global__ __launch_bounds__(256) void k_intra(
        const float* __restrict__ dp, const float* __restrict__ cnt,
        const float* __restrict__ centroid,
        float* __restrict__ out_intra, unsigned char* __restrict__ cid_g,
        float* __restrict__ dp_centroid, float* __restrict__ hard_negative) {
    __shared__ float ct[KC][K_N];        // 32 KB
    __shared__ float dpt[KC][BM + 4];    // 4.6 KB, row stride 144 B (16B-aligned)
    __shared__ float sqp[BM][8];
    __shared__ float rn[BM];
    int t = threadIdx.x;
    int row0 = blockIdx.x * BM;
    int tx = t & 63, ty = t >> 6;
    int c0 = tx * 4;
    int r0 = ty * 8;
    int sr = t >> 3, skq = t & 7;

    float acc[8][4];
    #pragma unroll
    for (int r = 0; r < 8; ++r)
        #pragma unroll
        for (int c = 0; c < 4; ++c) acc[r][c] = 0.f;
    float ss = 0.f;

    for (int kb = 0; kb < D_N; kb += KC) {
        __syncthreads();
        #pragma unroll
        for (int u = 0; u < 8; ++u) {
            int f4 = t + 256 * u;                 // 0..2047
            int k = f4 >> 6, c4 = (f4 & 63) << 2;
            *(float4*)&ct[k][c4] = *(const float4*)&cnt[(size_t)(kb + k) * K_N + c4];
        }
        {
            float4 v = *(const float4*)&dp[(size_t)(row0 + sr) * D_N + kb + skq * 4];
            ss += v.x * v.x + v.y * v.y + v.z * v.z + v.w * v.w;
            dpt[skq * 4 + 0][sr] = v.x;
            dpt[skq * 4 + 1][sr] = v.y;
            dpt[skq * 4 + 2][sr] = v.z;
            dpt[skq * 4 + 3][sr] = v.w;
        }
        __syncthreads();
        #pragma unroll
        for (int k = 0; k < KC; ++k) {
            float4 b4 = *(float4*)&ct[k][c0];
            float4 a0 = *(float4*)&dpt[k][r0];
            float4 a1 = *(float4*)&dpt[k][r0 + 4];
            float a[8] = {a0.x, a0.y, a0.z, a0.w, a1.x, a1.y, a1.z, a1.w};
            float b[4] = {b4.x, b4.y, b4.z, b4.w};
            #pragma unroll
            for (int r = 0; r < 8; ++r)
                #pragma unroll
                for (int c = 0; c < 4; ++c)
                    acc[r][c] += a[r] * b[c];
        }
    }

    // row norms
    sqp[sr][skq] = ss;
    __syncthreads();
    if (t < BM) {
        float s = 0.f;
        #pragma unroll
        for (int j = 0; j < 8; ++j) s += sqp[t][j];
        rn[t] = 1.0f / fmaxf(sqrtf(s), EPS_C);
    }
    __syncthreads();

    // per row: scale+store intra, wave top-2, cid + gather
    #pragma unroll 1
    for (int r = 0; r < 8; ++r) {
        int row = row0 + r0 + r;
        float rv = rn[r0 + r];
        float4 o;
        o.x = acc[r][0] * rv; o.y = acc[r][1] * rv;
        o.z = acc[r][2] * rv; o.w = acc[r][3] * rv;
        *(float4*)&out_intra[(size_t)row * K_N + c0] = o;

        float m1 = o.x, m2 = -1e30f;
        int i1 = c0, i2 = K_N;
        { float v = o.y; int id = c0 + 1;
          if (v > m1) { m2 = m1; i2 = i1; m1 = v; i1 = id; } else if (v > m2) { m2 = v; i2 = id; } }
        { float v = o.z; int id = c0 + 2;
          if (v > m1) { m2 = m1; i2 = i1; m1 = v; i1 = id; } else if (v > m2) { m2 = v; i2 = id; } }
        { float v = o.w; int id = c0 + 3;
          if (v > m1) { m2 = m1; i2 = i1; m1 = v; i1 = id; } else if (v > m2) { m2 = v; i2 = id; } }
        #pragma unroll
        for (int off = 32; off >= 1; off >>= 1) {
            float om1 = __shfl_xor(m1, off);
            int   oi1 = __shfl_xor(i1, off);
            float om2 = __shfl_xor(m2, off);
            int   oi2 = __shfl_xor(i2, off);
            if (top_better(om1, oi1, m1, i1)) {
                if (top_better(m1, i1, om2, oi2)) { m2 = m1; i2 = i1; }
                else                              { m2 = om2; i2 = oi2; }
                m1 = om1; i1 = oi1;
            } else if (top_better(om1, oi1, m2, i2)) {
                m2 = om1; i2 = oi1;
            }
        }
        if (tx == 0) cid_g[row] = (unsigned char)i1;

        const float4* s1 = (const float4*)(centroid + (size_t)i1 * D_N);
        const float4* s2 = (const float4*)(centroid + (size_t)i2 * D_N);
        float4* d1 = (float4*)(dp_centroid   + (size_t)row * D_N);
        float4* d2 = (float4*)(hard_negative + (size_t)row * D_N);
        #pragma unroll
        for (int u = 0; u < 3; ++u) {
            d1[tx + 64 * u] = s1[tx + 64 * u];
            d2[tx + 64 * u] = s2[tx + 64 * u];
        }
    }
}

// ---------------------------------------------------------------------------
// K3 v5: R8's reg-resident row pass + NONTEMPORAL loads/stores.
// bcs read-once -> nt load; dp_cluster/weights write-once -> nt store
// (bypass L2 write-allocate thrash: 512MB of streaming writes through
// 4MB/XCD L2 evicts everything). cid stays cached (reused by all blocks).
// ---------------------------------------------------------------------------
__global__ __launch_bounds__(256) void k_row(
        const float* __restrict__ bcs, const unsigned char* __restrict__ cid_g,
        float* __restrict__ dp_cluster, float* __restrict__ weights,
        float* __restrict__ partials) {
    int i = blockIdx.x;
    int t = threadIdx.x;
    __shared__ float red_se[4], red_fn[4];
    __shared__ float posb;
    const unsigned* cidw = (const unsigned*)cid_g;   // global, L2-hot

    // load row (nt) + cid words into regs
    const f4v* src = (const f4v*)(bcs + (size_t)i * B_N);
    f4v v[8];
    unsigned cw[8];
    #pragma unroll
    for (int u = 0; u < 8; ++u) {
        int f4 = t + 256 * u;
        v[u] = __builtin_nontemporal_load(&src[f4]);
        cw[u] = cidw[f4];
    }
    // owner thread publishes pos (static unroll, no runtime reg indexing)
    {
        int ti = (i >> 2) & 255;        // owning thread of float4 #(i/4)
        int ui = i >> 10;               // which u slot
        int q  = i & 3;
        if (t == ti) {
            float pe = 0.f;
            #pragma unroll
            for (int u = 0; u < 8; ++u)
                if (u == ui)
                    pe = (q == 0) ? v[u].x : (q == 1) ? v[u].y
                       : (q == 2) ? v[u].z : v[u].w;
            posb = pe;
        }
    }
    __syncthreads();                    // posb visible
    float pos = posb;
    unsigned myc = (unsigned)cid_g[i];

    float fn = 0.f, se = 0.f;
    float* dcrow = dp_cluster + (size_t)i * B_N;
    #pragma unroll
    for (int u = 0; u < 8; ++u) {
        int f4 = t + 256 * u;
        int j0 = f4 * 4;
        unsigned c = cw[u];
        f4v w = v[u], e, dc;
        {
            bool same = ((c & 255u) == myc) & (j0 != i);
            float delta = same ? (w.x - pos) : 0.f;
            fn += fmaxf(delta + ALPHA_C, 0.f) + fmaxf(-delta - BETA_C, 0.f);
            dc.x = same ? 1.0f : 0.f;
            e.x = __expf((j0 == i) ? NEG_INF_C : w.x);
        }
        {
            bool same = (((c >> 8) & 255u) == myc) & (j0 + 1 != i);
            float delta = same ? (w.y - pos) : 0.f;
            fn += fmaxf(delta + ALPHA_C, 0.f) + fmaxf(-delta - BETA_C, 0.f);
            dc.y = same ? 1.0f : 0.f;
            e.y = __expf((j0 + 1 == i) ? NEG_INF_C : w.y);
        }
        {
            bool same = (((c >> 16) & 255u) == myc) & (j0 + 2 != i);
            float delta = same ? (w.z - pos) : 0.f;
            fn += fmaxf(delta + ALPHA_C, 0.f) + fmaxf(-delta - BETA_C, 0.f);
            dc.z = same ? 1.0f : 0.f;
            e.z = __expf((j0 + 2 == i) ? NEG_INF_C : w.z);
        }
        {
            bool same = (((c >> 24) & 255u) == myc) & (j0 + 3 != i);
            float delta = same ? (w.w - pos) : 0.f;
            fn += fmaxf(delta + ALPHA_C, 0.f) + fmaxf(-delta - BETA_C, 0.f);
            dc.w = same ? 1.0f : 0.f;
            e.w = __expf((j0 + 3 == i) ? NEG_INF_C : w.w);
        }
        se += e.x + e.y + e.z + e.w;
        v[u] = e;                           // exp stays in regs
        __builtin_nontemporal_store(dc, (f4v*)&dcrow[j0]);
    }

    // joint se + fn reduce (one barrier)
    #pragma unroll
    for (int o = 32; o >= 1; o >>= 1) {
        se += __shfl_xor(se, o);
        fn += __shfl_xor(fn, o);
    }
    if ((t & 63) == 0) { red_se[t >> 6] = se; red_fn[t >> 6] = fn; }
    __syncthreads();
    se = red_se[0] + red_se[1] + red_se[2] + red_se[3];
    float inv = INV_WTEMP / se;

    // weights: base has odd float offset -> nt scalar stores
    float* wrow = weights + (size_t)i * B_N;
    #pragma unroll
    for (int u = 0; u < 8; ++u) {
        int j0 = (t + 256 * u) * 4;
        __builtin_nontemporal_store(v[u].x * inv, &wrow[j0]);
        __builtin_nontemporal_store(v[u].y * inv, &wrow[j0 + 1]);
        __builtin_nontemporal_store(v[u].z * inv, &wrow[j0 + 2]);
        __builtin_nontemporal_store(v[u].w * inv, &wrow[j0 + 3]);
    }

    if (t == 0)
        partials[i] = red_fn[0] + red_fn[1] + red_fn[2] + red_fn[3];
}

// ---------------------------------------------------------------------------
// K4: reduce 8192 per-block partials -> fn_loss (fixed order, deterministic)
// ---------------------------------------------------------------------------
__global__ __launch_bounds__(256) void k_final(
        const float* __restrict__ partials, float* __restrict__ out) {
    int t = threadIdx.x;
    __shared__ double red[4];
    double s = 0.0;
    #pragma unroll
    for (int u = 0; u < 32; ++u) s += (double)partials[t + 256 * u];
    #pragma unroll
    for (int o = 32; o >= 1; o >>= 1) s += __shfl_xor(s, o);
    if ((t & 63) == 0) red[t >> 6] = s;
    __syncthreads();
    if (t == 0)
        out[0] = (float)((red[0] + red[1] + red[2] + red[3])
                         / ((double)B_N * (double)B_N));
}

// ---------------------------------------------------------------------------
extern "C" void kernel_launch(void* const* d_in, const int* in_sizes, int n_in,
                              void* d_out, int out_size, void* d_ws, size_t ws_size,
                              hipStream_t stream) {
    const float* dp       = (const float*)d_in[0];
    const float* centroid = (const float*)d_in[1];
    const float* bcs      = (const float*)d_in[2];
    float* out = (float*)d_out;

    float* intra       = out;                       // [8192,256]
    float* dp_cluster  = out + 2097152;             // [8192,8192]
    float* dp_centroid = out + 69206016;            // [8192,768]
    float* hard_neg    = out + 75497472;            // [8192,768]
    float* fn_out      = out + 81788928;            // [1]
    float* weights     = out + 81788929;            // [8192,8192]

    char* ws = (char*)d_ws;
    float*         cnt      = (float*)(ws + 256);                      // 768*256*4
    unsigned char* cid      = (unsigned char*)(ws + 256 + 786432);     // 8192
    float*         partials = (float*)(ws + 256 + 786432 + 8192);      // 32768

    k_centroid_prep<<<K_N, 256, 0, stream>>>(centroid, cnt);
    k_intra<<<B_N / BM, 256, 0, stream>>>(dp, cnt, centroid, intra, cid,
                                          dp_centroid, hard_neg);
    k_row<<<B_N, 256, 0, stream>>>(bcs, cid, dp_cluster, weights, partials);
    k_final<<<1, 256, 0, stream>>>(partials, fn_out);
}